// Round 7
// baseline (1468.321 us; speedup 1.0000x reference)
//
#include <hip/hip_runtime.h>
#include <hip/hip_bf16.h>

#define GG 256
#define NPG 512
#define NN (GG*NPG)          // 131072 nodes
#define EE 1048576           // edges
#define FF 26
#define DEA 52
#define KK 128

// ---------------- node projection: pdst[n][52] = [Wf[:, :26]x | Ws[:, :26]x],
// psrc[n][52] = [Wf[:,26:52]x | Ws[:,26:52]x] ----------------
__global__ __launch_bounds__(256) void node_proj_k(
    const float* __restrict__ x, const float* __restrict__ Wf,
    const float* __restrict__ Ws, float* __restrict__ pdst,
    float* __restrict__ psrc) {
  int idx = blockIdx.x * 256 + threadIdx.x;   // n*52 + j
  if (idx >= NN * 52) return;
  int n = idx / 52, j = idx % 52;
  const float* W = (j < 26) ? Wf : Ws;
  int o = (j < 26) ? j : j - 26;
  const float* xr = x + n * FF;
  const float* wd = W + o * 104;       // dst part (cols 0..25)
  const float* wsp = W + o * 104 + 26; // src part (cols 26..51)
  float ad = 0.f, as = 0.f;
#pragma unroll
  for (int c = 0; c < FF; ++c) {
    float xv = xr[c];
    ad = fmaf(wd[c], xv, ad);
    as = fmaf(wsp[c], xv, as);
  }
  pdst[idx] = ad;
  psrc[n * 52 + j] = as;
}

// ---------------- edge assembly: msg = sigmoid(yf)*softplus(ys), atomic into acc[dst] ----
__global__ __launch_bounds__(256) void edge_k(
    const int* __restrict__ ei, const float* __restrict__ ea,
    const float* __restrict__ pdst, const float* __restrict__ psrc,
    const float* __restrict__ Wf, const float* __restrict__ bf,
    const float* __restrict__ Ws, const float* __restrict__ bs,
    float* __restrict__ acc) {
  __shared__ alignas(16) float ealds[32 * 56];
  __shared__ int dsts[32], srcs[32];
  int tid = threadIdx.x;
  int e0 = blockIdx.x * 32;
  if (tid < 32) {
    srcs[tid] = ei[e0 + tid];
    dsts[tid] = ei[EE + e0 + tid];
  }
  // stage 32 edge_attr rows (global index = e0*52 + f : perfectly coalesced)
  for (int f = tid; f < 32 * 52; f += 256) {
    int e = f / 52, i = f % 52;
    ealds[e * 56 + i] = ea[(size_t)e0 * 52 + f];
  }
  int o = tid & 31;
  int oc = (o < 26) ? o : 0;
  float wfr[52], wsr[52];
  const float* wfp = Wf + oc * 104 + 52;  // edge-attr part of gate f weights
  const float* wsp = Ws + oc * 104 + 52;
#pragma unroll
  for (int i = 0; i < 52; ++i) { wfr[i] = wfp[i]; wsr[i] = wsp[i]; }
  float bfv = bf[oc], bsv = bs[oc];
  __syncthreads();
  int slot = tid >> 5;
  for (int t = 0; t < 4; ++t) {
    int el = t * 8 + slot;
    int dst = dsts[el], src = srcs[el];
    float yf = bfv, ys = bsv;
    const float4* ar = (const float4*)&ealds[el * 56];
#pragma unroll
    for (int u = 0; u < 13; ++u) {
      float4 a = ar[u];
      yf = fmaf(wfr[4*u+0], a.x, yf); ys = fmaf(wsr[4*u+0], a.x, ys);
      yf = fmaf(wfr[4*u+1], a.y, yf); ys = fmaf(wsr[4*u+1], a.y, ys);
      yf = fmaf(wfr[4*u+2], a.z, yf); ys = fmaf(wsr[4*u+2], a.z, ys);
      yf = fmaf(wfr[4*u+3], a.w, yf); ys = fmaf(wsr[4*u+3], a.w, ys);
    }
    yf += pdst[(size_t)dst * 52 + oc] + psrc[(size_t)src * 52 + oc];
    ys += pdst[(size_t)dst * 52 + 26 + oc] + psrc[(size_t)src * 52 + 26 + oc];
    float sg = 1.0f / (1.0f + __expf(-yf));
    float sp = fmaxf(ys, 0.0f) + log1pf(__expf(-fabsf(ys)));
    float msg = sg * sp;
    if (o < 26) atomicAdd(&acc[(size_t)dst * FF + o], msg);
  }
}

// ---------------- h = tanh(x + acc) ----------------
__global__ __launch_bounds__(256) void upd_k(const float* __restrict__ xin,
                                             const float* __restrict__ acc,
                                             float* __restrict__ h) {
  int i = blockIdx.x * 256 + threadIdx.x;
  h[i] = tanhf(xin[i] + acc[i]);
}

// ---------------- per-graph softmax of interface_count ----------------
__global__ __launch_bounds__(512) void softmax_k(const float* __restrict__ ic,
                                                 float* __restrict__ s) {
  int g = blockIdx.x, j = threadIdx.x;
  __shared__ float red[512];
  float v = ic[g * NPG + j];
  red[j] = v; __syncthreads();
  for (int off = 256; off > 0; off >>= 1) {
    if (j < off) red[j] = fmaxf(red[j], red[j + off]);
    __syncthreads();
  }
  float mx = red[0]; __syncthreads();
  float e = expf(v - mx);
  red[j] = e; __syncthreads();
  for (int off = 256; off > 0; off >>= 1) {
    if (j < off) red[j] += red[j + off];
    __syncthreads();
  }
  s[g * NPG + j] = e / red[0];
}

// ---------------- transpose A[R][C] -> AT[C][R] ----------------
__global__ __launch_bounds__(256) void transpose_k(const float* __restrict__ A,
                                                   float* __restrict__ AT,
                                                   int R, int C) {
  int idx = blockIdx.x * 256 + threadIdx.x;
  if (idx >= R * C) return;
  int r = idx / C, c = idx % C;
  AT[c * R + r] = A[idx];
}

// ---------------- sort-pool + conv/dense head, one block per graph ----------------
__global__ __launch_bounds__(512) void head_k(
    const float* __restrict__ h1, const float* __restrict__ h2,
    const float* __restrict__ s_arr, const int* __restrict__ ipos,
    const float* __restrict__ Wc1, const float* __restrict__ bc1,
    const float* __restrict__ Wc2, const float* __restrict__ bc2,
    const float* __restrict__ W0T, const float* __restrict__ b0,
    const float* __restrict__ W1T, const float* __restrict__ b1,
    const float* __restrict__ W2, const float* __restrict__ b2,
    float* __restrict__ out) {
  int g = blockIdx.x, tid = threadIdx.x;
  __shared__ float kbuf[512];
  __shared__ int order[128];
  __shared__ float pooled[128][57];
  __shared__ float out1[16][128];
  __shared__ float mpool[16][64];
  __shared__ float h2c[1920];
  __shared__ float d0[512];
  __shared__ float d1[256];

  // sort key = f32 softmax value (the reference's key, incl. its f32 tie
  // pattern); stable descending with index tie-break == jnp.argsort(-s)
  int nj = ipos[g * NPG + tid];
  kbuf[tid] = s_arr[nj];
  __syncthreads();
  float kj = kbuf[tid];
  int rank = 0;
  for (int t = 0; t < 512; ++t) {
    float kt = kbuf[t];
    rank += (kt > kj) || (kt == kj && t < tid);  // stable descending
  }
  if (rank < KK) order[rank] = tid;
  __syncthreads();

  // gather pooled [128][53] = [h1 | h2 | s]
  for (int f = tid; f < KK * 53; f += 512) {
    int k = f / 53, l = f % 53;
    int node = ipos[g * NPG + order[k]];
    float v = (l < 26) ? h1[(size_t)node * 26 + l]
                       : (l < 52 ? h2[(size_t)node * 26 + (l - 26)] : s_arr[node]);
    pooled[k][l] = v;
  }
  __syncthreads();

  // conv1 (per-node linear 53->16) + relu
  for (int p = tid; p < 16 * 128; p += 512) {
    int o = p >> 7, k = p & 127;
    float a = bc1[o];
    for (int l = 0; l < 53; ++l) a = fmaf(pooled[k][l], Wc1[o * 53 + l], a);
    out1[o][k] = fmaxf(a, 0.f);
  }
  __syncthreads();

  // maxpool(2,2)
  for (int p = tid; p < 16 * 64; p += 512) {
    int o = p >> 6, q = p & 63;
    mpool[o][q] = fmaxf(out1[o][2 * q], out1[o][2 * q + 1]);
  }
  __syncthreads();

  // conv2 (16->32, k=5, valid) + relu, flattened as idx = o*60+q
  for (int p = tid; p < 32 * 60; p += 512) {
    int o = p / 60, q = p % 60;
    float a = bc2[o];
    for (int c = 0; c < 16; ++c)
#pragma unroll
      for (int t5 = 0; t5 < 5; ++t5)
        a = fmaf(mpool[c][q + t5], Wc2[(o * 16 + c) * 5 + t5], a);
    h2c[o * 60 + q] = fmaxf(a, 0.f);
  }
  __syncthreads();

  // dense0: 1920 -> 512, relu
  {
    float a = b0[tid];
    for (int q = 0; q < 1920; ++q) a = fmaf(h2c[q], W0T[q * 512 + tid], a);
    d0[tid] = fmaxf(a, 0.f);
  }
  __syncthreads();

  // dense1: 512 -> 256, relu
  if (tid < 256) {
    float a = b1[tid];
    for (int q = 0; q < 512; ++q) a = fmaf(d0[q], W1T[q * 256 + tid], a);
    d1[tid] = fmaxf(a, 0.f);
  }
  __syncthreads();

  // final: 256 -> 1
  if (tid < 256) kbuf[tid] = d1[tid] * W2[tid];
  __syncthreads();
  if (tid < 64) {
    float v = kbuf[tid] + kbuf[tid + 64] + kbuf[tid + 128] + kbuf[tid + 192];
    for (int off = 32; off > 0; off >>= 1) v += __shfl_down(v, off);
    if (tid == 0) out[g] = v + b2[0];
  }
}

extern "C" void kernel_launch(void* const* d_in, const int* in_sizes, int n_in,
                              void* d_out, int out_size, void* d_ws, size_t ws_size,
                              hipStream_t stream) {
  const float* x    = (const float*)d_in[0];
  const float* ea   = (const float*)d_in[1];
  const float* ic   = (const float*)d_in[2];
  const float* Wf1  = (const float*)d_in[3];
  const float* bf1  = (const float*)d_in[4];
  const float* Ws1  = (const float*)d_in[5];
  const float* bs1  = (const float*)d_in[6];
  const float* Wf2  = (const float*)d_in[7];
  const float* bf2  = (const float*)d_in[8];
  const float* Ws2  = (const float*)d_in[9];
  const float* bs2  = (const float*)d_in[10];
  const float* Wc1  = (const float*)d_in[11];
  const float* bc1  = (const float*)d_in[12];
  const float* Wc2  = (const float*)d_in[13];
  const float* bc2  = (const float*)d_in[14];
  const float* W0   = (const float*)d_in[15];
  const float* b0   = (const float*)d_in[16];
  const float* W1   = (const float*)d_in[17];
  const float* b1   = (const float*)d_in[18];
  const float* W2   = (const float*)d_in[19];
  const float* b2   = (const float*)d_in[20];
  const int*   ei   = (const int*)d_in[21];
  const int*   ipos = (const int*)d_in[23];
  float* out = (float*)d_out;

  const size_t N26 = (size_t)NN * 26;
  const size_t N52 = (size_t)NN * 52;
  float* ws = (float*)d_ws;
  float* acc  = ws;                 // N*26
  float* h1   = acc + N26;          // N*26
  float* h2   = h1 + N26;           // N*26
  float* pdst = h2 + N26;           // N*52
  float* psrc = pdst + N52;         // N*52
  float* sarr = psrc + N52;         // N
  float* W0T  = sarr + NN;          // 1920*512
  float* W1T  = W0T + 1920 * 512;   // 512*256

  // ---- layer 1 ----
  hipMemsetAsync(acc, 0, N26 * sizeof(float), stream);
  node_proj_k<<<(NN * 52) / 256, 256, 0, stream>>>(x, Wf1, Ws1, pdst, psrc);
  edge_k<<<EE / 32, 256, 0, stream>>>(ei, ea, pdst, psrc, Wf1, bf1, Ws1, bs1, acc);
  upd_k<<<(NN * 26) / 256, 256, 0, stream>>>(x, acc, h1);
  // ---- layer 2 ----
  hipMemsetAsync(acc, 0, N26 * sizeof(float), stream);
  node_proj_k<<<(NN * 52) / 256, 256, 0, stream>>>(h1, Wf2, Ws2, pdst, psrc);
  edge_k<<<EE / 32, 256, 0, stream>>>(ei, ea, pdst, psrc, Wf2, bf2, Ws2, bs2, acc);
  upd_k<<<(NN * 26) / 256, 256, 0, stream>>>(h1, acc, h2);
  // ---- softmax + head prep ----
  softmax_k<<<GG, 512, 0, stream>>>(ic, sarr);
  transpose_k<<<(512 * 1920) / 256, 256, 0, stream>>>(W0, W0T, 512, 1920);
  transpose_k<<<(256 * 512) / 256, 256, 0, stream>>>(W1, W1T, 256, 512);
  // ---- sort-pool + head ----
  head_k<<<GG, 512, 0, stream>>>(h1, h2, sarr, ipos, Wc1, bc1, Wc2, bc2,
                                 W0T, b0, W1T, b1, W2, b2, out);
}